// Round 9
// baseline (192.036 us; speedup 1.0000x reference)
//
#include <hip/hip_runtime.h>
#include <hip/hip_bf16.h>
#include <stdint.h>

// Problem constants (fixed by setup_inputs)
#define B_   64
#define H_   512
#define W_   512
#define S_N  1024      // n_segments
#define E_N  768       // embed_dim
#define K_N  768       // C*box*box = 3*16*16
#define HALF 8

typedef short bf16x8 __attribute__((ext_vector_type(8)));
typedef float f32x4  __attribute__((ext_vector_type(4)));

__device__ __forceinline__ unsigned short f2bf(float f) {
  union { float f; unsigned u; } v; v.f = f;
  unsigned u = v.u;
  u += 0x7FFF + ((u >> 16) & 1);   // RNE
  return (unsigned short)(u >> 16);
}

// ---------------- Phase 1: per-(b,s) packed sums, NO global atomics -----------
// [y:24 @39 | x:24 @15 | cnt:15 @0]; carry-free incremental pack.
__global__ void k_accum2(const int* __restrict__ seg,
                         unsigned long long* __restrict__ partials) {
  __shared__ unsigned long long ls[S_N];
  const int tid = threadIdx.x;
  const int xblk = blockIdx.x;   // 0..15
  const int b = blockIdx.y;
  for (int i = tid; i < S_N; i += 256) ls[i] = 0ULL;
  __syncthreads();
  const int pix0 = xblk * 16384;
  const int4* segb = (const int4*)(seg + (size_t)b * (H_ * W_) + pix0);
  for (int it = 0; it < 16; ++it) {
    int4 s4 = segb[it * 256 + tid];
    int p0 = pix0 + (it * 256 + tid) * 4;
    unsigned long long base = ((unsigned long long)(unsigned)(p0 >> 9) << 39)
                            | ((unsigned long long)(unsigned)(p0 & (W_ - 1)) << 15)
                            | 1ULL;
    #pragma unroll
    for (int j = 0; j < 4; ++j) {
      int s = (&s4.x)[j];
      s = ((unsigned)s < S_N) ? s : 0;
      atomicAdd(&ls[s], base + ((unsigned long long)j << 15));
    }
  }
  __syncthreads();
  unsigned long long* gp = partials + ((size_t)b * 16 + xblk) * S_N;
  for (int s = tid; s < S_N; s += 256) gp[s] = ls[s];
}

// -------- Phase 2 (merged): conv_w fp32->bf16 + partial-reduce/centroid -------
__global__ void k_prep(const float* __restrict__ w, unsigned short* __restrict__ wb,
                       const unsigned long long* __restrict__ partials,
                       int2* __restrict__ coords) {
  const int bid = blockIdx.x;
  const int tid = threadIdx.x;
  if (bid < 576) {
    int idx = bid * 256 + tid;                  // 147,456 float4s
    float4 v = ((const float4*)w)[idx];
    ushort4 o;
    o.x = f2bf(v.x); o.y = f2bf(v.y); o.z = f2bf(v.z); o.w = f2bf(v.w);
    ((ushort4*)wb)[idx] = o;
  } else {
    int m = (bid - 576) * 256 + tid;            // 65536 = B*S
    int b = m >> 10, s = m & (S_N - 1);
    unsigned sx = 0, sy = 0, c = 0;
    #pragma unroll
    for (int x = 0; x < 16; ++x) {
      unsigned long long v = partials[((size_t)b * 16 + x) * S_N + s];
      c  += (unsigned)(v & 0x7FFFULL);
      sx += (unsigned)((v >> 15) & 0xFFFFFFULL);
      sy += (unsigned)(v >> 39);
    }
    float xc = 0.f, yc = 0.f;
    if (c > 0) {
      float cf = (float)c;
      xc = (float)sx / cf;   // IEEE f32 div of exact ints == reference
      yc = (float)sy / cf;
    }
    coords[m] = make_int2((int)floorf(xc), (int)floorf(yc));
  }
}

// ---------------- Phase 3a: COALESCED patch gather -> bf16 A[M][K] ------------
__global__ __launch_bounds__(256) void k_patch2(const float* __restrict__ img,
                                                const int2* __restrict__ coords,
                                                unsigned short* __restrict__ A) {
  const int g  = threadIdx.x >> 4;    // 0..15 : patch slot in block
  const int lx = threadIdx.x & 15;    // x-offset lane
  const int m  = blockIdx.x * 16 + g;
  const int2 cc = coords[m];
  const int b  = m >> 10;
  const int x  = cc.x - HALF + lx;
  const int y0 = cc.y - HALF;
  const bool xok = (unsigned)x < W_;
  const int xs = xok ? x : 0;
  const float* ib = img + (size_t)b * 3 * H_ * W_;
  unsigned short* Am = A + (size_t)m * K_N + lx;
  #pragma unroll
  for (int r = 0; r < 48; ++r) {      // r = c*16 + h
    const int y = y0 + (r & 15);
    const bool ok = xok && ((unsigned)y < H_);
    const int ys = ((unsigned)y < H_) ? y : 0;
    float v = ib[(((r >> 4) << 9) + ys) * W_ + xs];
    v = ok ? v : 0.f;
    Am[r * 16] = f2bf(v);
  }
}

// ------- Phase 3b: 128x128 8-phase bf16 MFMA GEMM, 2 blocks/CU (TLP fix) ------
// 256 thr = 4 waves (2x2); wave-out 64x64 (acc[4][4]); BK=64; LDS 64 KiB dbuf.
// BUGFIX vs r8: stage halves are STRIPE-INTERLEAVED to match quadrant reads.
// LOAD_*2(Q) reads rows {wr*64 + Q*32 + 0..31} across waves = stripe
// {Q*32..+31} u {64+Q*32..+31}; stage half h must write exactly that stripe:
// rowbase = (idx>>2)*64 + h*32 + (idx&3)*8. (The r8 version staged contiguous
// halves 0..63/64..127 -> wrong-tile data + same-phase LDS overwrite race.)
__global__ __launch_bounds__(256, 2) void k_gemm2b(
    const unsigned short* __restrict__ Amat,
    const unsigned short* __restrict__ Bmat,
    float* __restrict__ out) {
  __shared__ unsigned short As[2][128 * 64];
  __shared__ unsigned short Bs[2][128 * 64];
  const int tid  = threadIdx.x;
  const int wave = tid >> 6;
  const int lane = tid & 63;

  // bijective XCD remap: 3072 blocks = 8 XCDs x 384; bn fastest
  const int virt = (blockIdx.x & 7) * 384 + (blockIdx.x >> 3);
  const int bm = virt / 6;           // 0..511
  const int bn = virt - bm * 6;      // 0..5
  const int gm0 = bm * 128;
  const int gn0 = bn * 128;

  const int wr = wave >> 1;          // 0..1
  const int wc = wave & 1;           // 0..1
  const int rlo  = lane & 15;
  const int rsel = lane & 7;
  const int sub  = lane >> 4;        // 0..3
  int swz[2];
  swz[0] = ((0 + sub) ^ rsel) * 8;   // shorts offset, kk=0
  swz[1] = ((4 + sub) ^ rsel) * 8;   // kk=1

  const int srow = lane >> 3;             // 0..7
  const int sch  = (lane & 7) ^ srow;     // pre-swizzled source chunk

  f32x4 acc[4][4];
  #pragma unroll
  for (int i = 0; i < 4; ++i)
    #pragma unroll
    for (int j = 0; j < 4; ++j)
      acc[i][j] = (f32x4){0.f, 0.f, 0.f, 0.f};

  // stage one 64-row stripe-half (8 KB): 2 gload_lds/thread, idx = wave*2+l.
  // half h covers rows {h*32..h*32+31} u {64+h*32..64+h*32+31}.
  auto stageA = [&](int buf, int mh, int k0) {
    #pragma unroll
    for (int l = 0; l < 2; ++l) {
      int idx = wave * 2 + l;                                  // 0..7
      int rowbase = (idx >> 2) * 64 + mh * 32 + (idx & 3) * 8;
      const unsigned short* g = Amat + (size_t)(gm0 + rowbase + srow) * K_N + k0 + sch * 8;
      __builtin_amdgcn_global_load_lds((const __attribute__((address_space(1))) void*)g,
        (__attribute__((address_space(3))) void*)&As[buf][rowbase * 64], 16, 0, 0);
    }
  };
  auto stageB = [&](int buf, int nh, int k0) {
    #pragma unroll
    for (int l = 0; l < 2; ++l) {
      int idx = wave * 2 + l;
      int rowbase = (idx >> 2) * 64 + nh * 32 + (idx & 3) * 8;
      const unsigned short* g = Bmat + (size_t)(gn0 + rowbase + srow) * K_N + k0 + sch * 8;
      __builtin_amdgcn_global_load_lds((const __attribute__((address_space(1))) void*)g,
        (__attribute__((address_space(3))) void*)&Bs[buf][rowbase * 64], 16, 0, 0);
    }
  };

  bf16x8 a2[2][2], b2[2][2];

#define LOAD_A2(BUF, QM) \
  _Pragma("unroll") for (int mi = 0; mi < 2; ++mi) \
  _Pragma("unroll") for (int kk = 0; kk < 2; ++kk) \
    a2[mi][kk] = *(const bf16x8*)&As[BUF][(wr * 64 + (QM) * 32 + mi * 16 + rlo) * 64 + swz[kk]];
#define LOAD_B2(BUF, QN) \
  _Pragma("unroll") for (int ni = 0; ni < 2; ++ni) \
  _Pragma("unroll") for (int kk = 0; kk < 2; ++kk) \
    b2[ni][kk] = *(const bf16x8*)&Bs[BUF][(wc * 64 + (QN) * 32 + ni * 16 + rlo) * 64 + swz[kk]];
#define MFMA_Q(QM, QN) \
  __builtin_amdgcn_s_setprio(1); \
  _Pragma("unroll") for (int mi = 0; mi < 2; ++mi) \
  _Pragma("unroll") for (int ni = 0; ni < 2; ++ni) \
  _Pragma("unroll") for (int kk = 0; kk < 2; ++kk) \
    acc[(QM) * 2 + mi][(QN) * 2 + ni] = __builtin_amdgcn_mfma_f32_16x16x32_bf16( \
        a2[mi][kk], b2[ni][kk], acc[(QM) * 2 + mi][(QN) * 2 + ni], 0, 0, 0); \
  __builtin_amdgcn_s_setprio(0);
#define SYNC_MFMA \
  __builtin_amdgcn_s_barrier(); \
  asm volatile("s_waitcnt lgkmcnt(0)" ::: "memory"); \
  __builtin_amdgcn_sched_barrier(0);
#define ENDPH __builtin_amdgcn_s_barrier();

  // Prologue: tile0 fully into buf0; tile1's A.h0 + B.h1 into buf1.
  stageA(0, 0, 0); stageA(0, 1, 0); stageB(0, 0, 0); stageB(0, 1, 0);
  stageA(1, 0, 64); stageB(1, 1, 64);
  asm volatile("s_waitcnt vmcnt(4)" ::: "memory");   // tile0's 8 loads landed
  __builtin_amdgcn_s_barrier();

  // Main: 5 iters cover tiles 0..9 (2 per iter); tail covers 10,11.
  for (int i = 0; i < 5; ++i) {
    const int kB = (2 * i + 1) * 64;
    const int kC = (2 * i + 2) * 64;
    const int kD = (2 * i + 3) * 64;
    // P1: tile 2i (buf0) Q(0,0)
    LOAD_A2(0, 0); LOAD_B2(0, 0);
    stageB(1, 0, kB);
    SYNC_MFMA; MFMA_Q(0, 0); ENDPH;
    // P2: Q(0,1)
    LOAD_B2(0, 1);
    stageA(1, 1, kB);
    SYNC_MFMA; MFMA_Q(0, 1); ENDPH;
    // P3: Q(1,1)  (reads A-h1; stages A-h0 — disjoint stripes now)
    LOAD_A2(0, 1);
    stageA(0, 0, kC);
    SYNC_MFMA; MFMA_Q(1, 1); ENDPH;
    // P4: Q(1,0); tile 2i+1 fully landed after this wait
    LOAD_B2(0, 0);
    stageB(0, 1, kC);
    asm volatile("s_waitcnt vmcnt(4)" ::: "memory");
    SYNC_MFMA; MFMA_Q(1, 0); ENDPH;
    // P5: tile 2i+1 (buf1) Q(0,0)
    LOAD_A2(1, 0); LOAD_B2(1, 0);
    stageB(0, 0, kC);
    SYNC_MFMA; MFMA_Q(0, 0); ENDPH;
    // P6: Q(0,1)
    LOAD_B2(1, 1);
    stageA(0, 1, kC);
    SYNC_MFMA; MFMA_Q(0, 1); ENDPH;
    // P7: Q(1,1)
    LOAD_A2(1, 1);
    stageA(1, 0, kD);
    SYNC_MFMA; MFMA_Q(1, 1); ENDPH;
    // P8: Q(1,0); tile 2i+2 fully landed after this wait
    LOAD_B2(1, 0);
    stageB(1, 1, kD);
    asm volatile("s_waitcnt vmcnt(4)" ::: "memory");
    SYNC_MFMA; MFMA_Q(1, 0); ENDPH;
  }

  // Tail: tiles 10 (buf0), 11 (buf1). Remaining stages: B11.h0, A11.h1.
  {
    const int k11 = 11 * 64;
    // T1
    LOAD_A2(0, 0); LOAD_B2(0, 0);
    stageB(1, 0, k11);
    SYNC_MFMA; MFMA_Q(0, 0); ENDPH;
    // T2
    LOAD_B2(0, 1);
    stageA(1, 1, k11);
    SYNC_MFMA; MFMA_Q(0, 1); ENDPH;
    // T3
    LOAD_A2(0, 1);
    SYNC_MFMA; MFMA_Q(1, 1); ENDPH;
    // T4: FULL drain — tile 11's stages (issued T1/T2) must land
    LOAD_B2(0, 0);
    asm volatile("s_waitcnt vmcnt(0)" ::: "memory");
    SYNC_MFMA; MFMA_Q(1, 0); ENDPH;
    // T5
    LOAD_A2(1, 0); LOAD_B2(1, 0);
    SYNC_MFMA; MFMA_Q(0, 0); ENDPH;
    // T6
    LOAD_B2(1, 1);
    SYNC_MFMA; MFMA_Q(0, 1); ENDPH;
    // T7
    LOAD_A2(1, 1);
    SYNC_MFMA; MFMA_Q(1, 1); ENDPH;
    // T8
    LOAD_B2(1, 0);
    SYNC_MFMA; MFMA_Q(1, 0); ENDPH;
  }

  // Epilogue: C/D layout col=lane&15, row=(lane>>4)*4+reg
  const int row0 = gm0 + wr * 64 + (lane >> 4) * 4;
  const int col0 = gn0 + wc * 64 + (lane & 15);
  #pragma unroll
  for (int mi = 0; mi < 4; ++mi)
    #pragma unroll
    for (int ni = 0; ni < 4; ++ni)
      #pragma unroll
      for (int r = 0; r < 4; ++r)
        out[(size_t)(row0 + mi * 16 + r) * E_N + (col0 + ni * 16)] = acc[mi][ni][r];
#undef LOAD_A2
#undef LOAD_B2
#undef MFMA_Q
#undef SYNC_MFMA
#undef ENDPH
}

extern "C" void kernel_launch(void* const* d_in, const int* in_sizes, int n_in,
                              void* d_out, int out_size, void* d_ws, size_t ws_size,
                              hipStream_t stream) {
  const float* img = (const float*)d_in[0];
  const int*   seg = (const int*)d_in[1];
  const float* cw  = (const float*)d_in[2];
  float* out = (float*)d_out;
  char* ws = (char*)d_ws;

  unsigned long long* partials = (unsigned long long*)ws;    // 8,388,608 B
  int2*           coords = (int2*)(ws + 8388608);            //   524,288 B
  unsigned short* Bmat   = (unsigned short*)(ws + 8912896);  // 1,179,648 B
  unsigned short* Amat   = (unsigned short*)(ws + 10092544); // 100,663,296 B

  k_accum2<<<dim3(16, 64), 256, 0, stream>>>(seg, partials);
  k_prep<<<832, 256, 0, stream>>>(cw, Bmat, partials, coords);
  k_patch2<<<4096, 256, 0, stream>>>(img, coords, Amat);
  k_gemm2b<<<3072, 256, 0, stream>>>(Amat, Bmat, out);
}

// Round 10
// 182.458 us; speedup vs baseline: 1.0525x; 1.0525x over previous
//
#include <hip/hip_runtime.h>
#include <hip/hip_bf16.h>
#include <stdint.h>

// Problem constants (fixed by setup_inputs)
#define B_   64
#define H_   512
#define W_   512
#define S_N  1024      // n_segments
#define E_N  768       // embed_dim
#define K_N  768       // C*box*box = 3*16*16
#define HALF 8

typedef short bf16x8 __attribute__((ext_vector_type(8)));
typedef float f32x4  __attribute__((ext_vector_type(4)));

__device__ __forceinline__ unsigned short f2bf(float f) {
  union { float f; unsigned u; } v; v.f = f;
  unsigned u = v.u;
  u += 0x7FFF + ((u >> 16) & 1);   // RNE
  return (unsigned short)(u >> 16);
}

// ---------------- Phase 1: per-(b,s) packed sums, NO global atomics -----------
__global__ void k_accum2(const int* __restrict__ seg,
                         unsigned long long* __restrict__ partials) {
  __shared__ unsigned long long ls[S_N];
  const int tid = threadIdx.x;
  const int xblk = blockIdx.x;   // 0..15
  const int b = blockIdx.y;
  for (int i = tid; i < S_N; i += 256) ls[i] = 0ULL;
  __syncthreads();
  const int pix0 = xblk * 16384;
  const int4* segb = (const int4*)(seg + (size_t)b * (H_ * W_) + pix0);
  for (int it = 0; it < 16; ++it) {
    int4 s4 = segb[it * 256 + tid];
    int p0 = pix0 + (it * 256 + tid) * 4;
    unsigned long long base = ((unsigned long long)(unsigned)(p0 >> 9) << 39)
                            | ((unsigned long long)(unsigned)(p0 & (W_ - 1)) << 15)
                            | 1ULL;
    #pragma unroll
    for (int j = 0; j < 4; ++j) {
      int s = (&s4.x)[j];
      s = ((unsigned)s < S_N) ? s : 0;
      atomicAdd(&ls[s], base + ((unsigned long long)j << 15));
    }
  }
  __syncthreads();
  unsigned long long* gp = partials + ((size_t)b * 16 + xblk) * S_N;
  for (int s = tid; s < S_N; s += 256) gp[s] = ls[s];
}

// -------- Phase 2 (merged): conv_w fp32->bf16 + partial-reduce/centroid -------
__global__ void k_prep(const float* __restrict__ w, unsigned short* __restrict__ wb,
                       const unsigned long long* __restrict__ partials,
                       int2* __restrict__ coords) {
  const int bid = blockIdx.x;
  const int tid = threadIdx.x;
  if (bid < 576) {
    int idx = bid * 256 + tid;                  // 147,456 float4s
    float4 v = ((const float4*)w)[idx];
    ushort4 o;
    o.x = f2bf(v.x); o.y = f2bf(v.y); o.z = f2bf(v.z); o.w = f2bf(v.w);
    ((ushort4*)wb)[idx] = o;
  } else {
    int m = (bid - 576) * 256 + tid;            // 65536 = B*S
    int b = m >> 10, s = m & (S_N - 1);
    unsigned sx = 0, sy = 0, c = 0;
    #pragma unroll
    for (int x = 0; x < 16; ++x) {
      unsigned long long v = partials[((size_t)b * 16 + x) * S_N + s];
      c  += (unsigned)(v & 0x7FFFULL);
      sx += (unsigned)((v >> 15) & 0xFFFFFFULL);
      sy += (unsigned)(v >> 39);
    }
    float xc = 0.f, yc = 0.f;
    if (c > 0) {
      float cf = (float)c;
      xc = (float)sx / cf;   // IEEE f32 div of exact ints == reference
      yc = (float)sy / cf;
    }
    coords[m] = make_int2((int)floorf(xc), (int)floorf(yc));
  }
}

// ---------------- Phase 3a: COALESCED patch gather -> bf16 A[M][K] ------------
__global__ __launch_bounds__(256) void k_patch2(const float* __restrict__ img,
                                                const int2* __restrict__ coords,
                                                unsigned short* __restrict__ A) {
  const int g  = threadIdx.x >> 4;    // 0..15 : patch slot in block
  const int lx = threadIdx.x & 15;    // x-offset lane
  const int m  = blockIdx.x * 16 + g;
  const int2 cc = coords[m];
  const int b  = m >> 10;
  const int x  = cc.x - HALF + lx;
  const int y0 = cc.y - HALF;
  const bool xok = (unsigned)x < W_;
  const int xs = xok ? x : 0;
  const float* ib = img + (size_t)b * 3 * H_ * W_;
  unsigned short* Am = A + (size_t)m * K_N + lx;
  #pragma unroll
  for (int r = 0; r < 48; ++r) {      // r = c*16 + h
    const int y = y0 + (r & 15);
    const bool ok = xok && ((unsigned)y < H_);
    const int ys = ((unsigned)y < H_) ? y : 0;
    float v = ib[(((r >> 4) << 9) + ys) * W_ + xs];
    v = ok ? v : 0.f;
    Am[r * 16] = f2bf(v);
  }
}

// ---- Phase 3b: 256x256 SINGLE-BUFFERED simple-loop GEMM, 2 blocks/CU ---------
// The r2/r7/r9 lesson: all barrier-phased 1-block/CU structures stall at
// ~110-123us because barrier drains and the 262KB C-write burst have nothing
// to overlap with. This kernel trades software pipelining for BLOCK-level TLP:
// 64KB LDS (As+Bs, single buffer) -> 2 blocks/CU; per tile {barrier, stage,
// vmcnt(0), barrier, 64 MFMA/wave}. While one block drains, the co-resident
// block computes (m114). T2 both-sides swizzle; bijective XCD remap with
// bn-fastest so each bm-trio shares its A panel in one XCD's L2.
__global__ __launch_bounds__(512) void k_gemms(
    const unsigned short* __restrict__ Amat,
    const unsigned short* __restrict__ Bmat,
    float* __restrict__ out) {
  __shared__ unsigned short As[256 * 64];   // 32 KB
  __shared__ unsigned short Bs[256 * 64];   // 32 KB
  const int tid  = threadIdx.x;
  const int wave = tid >> 6;
  const int lane = tid & 63;

  // bijective XCD remap: 768 blocks = 8 XCDs x 96; bn fastest
  const int virt = (blockIdx.x & 7) * 96 + (blockIdx.x >> 3);
  const int bm = virt / 3;
  const int bn = virt - bm * 3;
  const int gm0 = bm * 256;
  const int gn0 = bn * 256;

  const int wr = wave >> 2;          // 0..1 : wave row (128 rows)
  const int wc = wave & 3;           // 0..3 : wave col (64 cols)
  const int rlo  = lane & 15;
  const int rsel = lane & 7;
  const int sub  = lane >> 4;        // 0..3
  int swz[2];
  swz[0] = ((0 + sub) ^ rsel) * 8;   // shorts offset, kk=0
  swz[1] = ((4 + sub) ^ rsel) * 8;   // kk=1

  f32x4 acc[8][4];
  #pragma unroll
  for (int i = 0; i < 8; ++i)
    #pragma unroll
    for (int j = 0; j < 4; ++j)
      acc[i][j] = (f32x4){0.f, 0.f, 0.f, 0.f};

  // Stage a full 256x64 tile (2048 16B segs): 4 gload_lds per thread.
  // seg s -> row s>>3, chunk s&7; source chunk pre-XORed with row&7 (T2).
  // LDS dest base is wave-uniform; HW writes base + lane*16 = seg*16. [m104]
  auto stage = [&](const unsigned short* __restrict__ mat,
                   unsigned short* __restrict__ lds, int g0, int k0) {
    #pragma unroll
    for (int i = 0; i < 4; ++i) {
      int seg = i * 512 + tid;
      int row = seg >> 3;
      int csrc = (seg & 7) ^ (row & 7);
      const unsigned short* g = mat + (size_t)(g0 + row) * K_N + k0 + csrc * 8;
      __builtin_amdgcn_global_load_lds((const __attribute__((address_space(1))) void*)g,
        (__attribute__((address_space(3))) void*)&lds[(i * 512 + wave * 64) * 8], 16, 0, 0);
    }
  };

  for (int kt = 0; kt < 12; ++kt) {
    const int k0 = kt * 64;
    __syncthreads();                 // previous tile's reads done before overwrite
    stage(Amat, As, gm0, k0);
    stage(Bmat, Bs, gn0, k0);
    asm volatile("s_waitcnt vmcnt(0)" ::: "memory");
    __syncthreads();                 // tile visible to all waves

    #pragma unroll
    for (int kk = 0; kk < 2; ++kk) {
      bf16x8 av[8], bv[4];
      #pragma unroll
      for (int mi = 0; mi < 8; ++mi)
        av[mi] = *(const bf16x8*)&As[(wr * 128 + mi * 16 + rlo) * 64 + swz[kk]];
      #pragma unroll
      for (int ni = 0; ni < 4; ++ni)
        bv[ni] = *(const bf16x8*)&Bs[(wc * 64 + ni * 16 + rlo) * 64 + swz[kk]];
      __builtin_amdgcn_s_setprio(1);
      #pragma unroll
      for (int mi = 0; mi < 8; ++mi)
        #pragma unroll
        for (int ni = 0; ni < 4; ++ni)
          acc[mi][ni] = __builtin_amdgcn_mfma_f32_16x16x32_bf16(
              av[mi], bv[ni], acc[mi][ni], 0, 0, 0);
      __builtin_amdgcn_s_setprio(0);
    }
  }

  // Epilogue: C/D layout col=lane&15, row=(lane>>4)*4+reg
  const int row0 = gm0 + wr * 128 + (lane >> 4) * 4;
  const int col0 = gn0 + wc * 64 + (lane & 15);
  #pragma unroll
  for (int mi = 0; mi < 8; ++mi)
    #pragma unroll
    for (int ni = 0; ni < 4; ++ni)
      #pragma unroll
      for (int r = 0; r < 4; ++r)
        out[(size_t)(row0 + mi * 16 + r) * E_N + (col0 + ni * 16)] = acc[mi][ni][r];
}

extern "C" void kernel_launch(void* const* d_in, const int* in_sizes, int n_in,
                              void* d_out, int out_size, void* d_ws, size_t ws_size,
                              hipStream_t stream) {
  const float* img = (const float*)d_in[0];
  const int*   seg = (const int*)d_in[1];
  const float* cw  = (const float*)d_in[2];
  float* out = (float*)d_out;
  char* ws = (char*)d_ws;

  unsigned long long* partials = (unsigned long long*)ws;    // 8,388,608 B
  int2*           coords = (int2*)(ws + 8388608);            //   524,288 B
  unsigned short* Bmat   = (unsigned short*)(ws + 8912896);  // 1,179,648 B
  unsigned short* Amat   = (unsigned short*)(ws + 10092544); // 100,663,296 B

  k_accum2<<<dim3(16, 64), 256, 0, stream>>>(seg, partials);
  k_prep<<<832, 256, 0, stream>>>(cw, Bmat, partials, coords);
  k_patch2<<<4096, 256, 0, stream>>>(img, coords, Amat);
  k_gemms<<<768, 512, 0, stream>>>(Amat, Bmat, out);
}

// Round 11
// 174.318 us; speedup vs baseline: 1.1016x; 1.0467x over previous
//
#include <hip/hip_runtime.h>
#include <hip/hip_bf16.h>
#include <stdint.h>

// Problem constants (fixed by setup_inputs)
#define B_   64
#define H_   512
#define W_   512
#define S_N  1024      // n_segments
#define E_N  768       // embed_dim
#define K_N  768       // C*box*box = 3*16*16
#define HALF 8

typedef short bf16x8 __attribute__((ext_vector_type(8)));
typedef float f32x4  __attribute__((ext_vector_type(4)));

__device__ __forceinline__ unsigned short f2bf(float f) {
  union { float f; unsigned u; } v; v.f = f;
  unsigned u = v.u;
  u += 0x7FFF + ((u >> 16) & 1);   // RNE
  return (unsigned short)(u >> 16);
}

// ------ Phase 1 (merged): per-(b,s) packed sums (blocks 0..1023) +
//        conv_w fp32->bf16 (blocks 1024..1599) ---------------------------------
// Pack [y:24 @39 | x:24 @15 | cnt:15 @0]; carry-free incremental pack.
__global__ void k_accum_convw(const int* __restrict__ seg,
                              unsigned long long* __restrict__ partials,
                              const float* __restrict__ w,
                              unsigned short* __restrict__ wb) {
  __shared__ unsigned long long ls[S_N];
  const int bid = blockIdx.x;
  const int tid = threadIdx.x;
  if (bid >= 1024) {                 // conv_w conversion: 147,456 float4s
    int idx = (bid - 1024) * 256 + tid;
    float4 v = ((const float4*)w)[idx];
    ushort4 o;
    o.x = f2bf(v.x); o.y = f2bf(v.y); o.z = f2bf(v.z); o.w = f2bf(v.w);
    ((ushort4*)wb)[idx] = o;
    return;
  }
  const int xblk = bid & 15;         // 0..15
  const int b    = bid >> 4;         // 0..63
  for (int i = tid; i < S_N; i += 256) ls[i] = 0ULL;
  __syncthreads();
  const int pix0 = xblk * 16384;
  const int4* segb = (const int4*)(seg + (size_t)b * (H_ * W_) + pix0);
  for (int it = 0; it < 16; ++it) {
    int4 s4 = segb[it * 256 + tid];
    int p0 = pix0 + (it * 256 + tid) * 4;
    unsigned long long base = ((unsigned long long)(unsigned)(p0 >> 9) << 39)
                            | ((unsigned long long)(unsigned)(p0 & (W_ - 1)) << 15)
                            | 1ULL;
    #pragma unroll
    for (int j = 0; j < 4; ++j) {
      int s = (&s4.x)[j];
      s = ((unsigned)s < S_N) ? s : 0;
      atomicAdd(&ls[s], base + ((unsigned long long)j << 15));
    }
  }
  __syncthreads();
  unsigned long long* gp = partials + ((size_t)b * 16 + xblk) * S_N;
  for (int s = tid; s < S_N; s += 256) gp[s] = ls[s];
}

// ------ Phase 2 (merged): per-patch centroid reduce + COALESCED gather --------
// 16-lane group <-> one patch. Lane lx loads partial[xblk=lx], shfl_xor width-16
// reduce -> (x_min, y_min) in-register (k_prep/coords buffer eliminated).
// Gather: lane = x-offset -> per load instr a wave touches 4 patch rows
// (~6-8 cache lines), the r6 lesson.
__global__ __launch_bounds__(256) void k_patch3(const float* __restrict__ img,
                                                const unsigned long long* __restrict__ partials,
                                                unsigned short* __restrict__ A) {
  const int g  = threadIdx.x >> 4;    // 0..15 : patch slot in block
  const int lx = threadIdx.x & 15;    // x-offset lane
  const int m  = blockIdx.x * 16 + g;
  const int b  = m >> 10;
  const int s  = m & (S_N - 1);
  // centroid: reduce the 16 x-block partials across the 16-lane group
  unsigned long long v = partials[((size_t)b * 16 + lx) * S_N + s];
  unsigned c  = (unsigned)(v & 0x7FFFULL);
  unsigned sx = (unsigned)((v >> 15) & 0xFFFFFFULL);
  unsigned sy = (unsigned)(v >> 39);
  #pragma unroll
  for (int off = 8; off; off >>= 1) {
    c  += __shfl_xor(c,  off, 16);
    sx += __shfl_xor(sx, off, 16);
    sy += __shfl_xor(sy, off, 16);
  }
  int xmin = 0, ymin = 0;
  if (c > 0) {
    float cf = (float)c;
    xmin = (int)floorf((float)sx / cf);   // IEEE f32 div of exact ints == ref
    ymin = (int)floorf((float)sy / cf);
  }
  const int x  = xmin - HALF + lx;
  const int y0 = ymin - HALF;
  const bool xok = (unsigned)x < W_;
  const int xs = xok ? x : 0;
  const float* ib = img + (size_t)b * 3 * H_ * W_;
  unsigned short* Am = A + (size_t)m * K_N + lx;
  #pragma unroll
  for (int r = 0; r < 48; ++r) {      // r = c*16 + h
    const int y = y0 + (r & 15);
    const bool ok = xok && ((unsigned)y < H_);
    const int ys = ((unsigned)y < H_) ? y : 0;
    float pv = ib[(((r >> 4) << 9) + ys) * W_ + xs];
    pv = ok ? pv : 0.f;
    Am[r * 16] = f2bf(pv);
  }
}

// ------ Phase 3: 256x256 8-phase bf16 MFMA GEMM (r7 best: 111.5us),
//        tail peeled with vmcnt(0) (fixes the latent tile-11 stage race) -------
__global__ __launch_bounds__(512) void k_gemm8(
    const unsigned short* __restrict__ Amat,
    const unsigned short* __restrict__ Bmat,
    float* __restrict__ out) {
  __shared__ unsigned short As[2][256 * 64];
  __shared__ unsigned short Bs[2][256 * 64];
  const int tid  = threadIdx.x;
  const int wave = tid >> 6;
  const int lane = tid & 63;

  // bijective XCD remap: 768 blocks = 8 XCDs x 96
  const int virt = (blockIdx.x & 7) * 96 + (blockIdx.x >> 3);
  const int bm = virt / 3;
  const int bn = virt - bm * 3;
  const int gm0 = bm * 256;
  const int gn0 = bn * 256;

  const int wr = wave >> 2;          // 0..1
  const int wc = wave & 3;           // 0..3
  const int rlo  = lane & 15;
  const int rsel = lane & 7;
  const int sub  = lane >> 4;        // 0..3
  int swz[2];
  swz[0] = ((0 + sub) ^ rsel) * 8;   // shorts offset, kk=0
  swz[1] = ((4 + sub) ^ rsel) * 8;   // kk=1

  const int srow = lane >> 3;             // row within 8-row group
  const int sch  = (lane & 7) ^ srow;     // pre-swizzled source chunk

  f32x4 acc[8][4];
  #pragma unroll
  for (int i = 0; i < 8; ++i)
    #pragma unroll
    for (int j = 0; j < 4; ++j)
      acc[i][j] = (f32x4){0.f, 0.f, 0.f, 0.f};

  auto stageA = [&](int buf, int mh, int k0) {
    #pragma unroll
    for (int l = 0; l < 2; ++l) {
      int idx = wave * 2 + l;                                // 0..15
      int rowbase = mh * 64 + (idx >> 3) * 128 + (idx & 7) * 8;
      const unsigned short* g = Amat + (size_t)(gm0 + rowbase + srow) * K_N + k0 + sch * 8;
      __builtin_amdgcn_global_load_lds((const __attribute__((address_space(1))) void*)g,
        (__attribute__((address_space(3))) void*)&As[buf][rowbase * 64], 16, 0, 0);
    }
  };
  auto stageB = [&](int buf, int nh, int k0) {
    #pragma unroll
    for (int l = 0; l < 2; ++l) {
      int idx = wave * 2 + l;
      int rowbase = (idx >> 2) * 64 + nh * 32 + (idx & 3) * 8;
      const unsigned short* g = Bmat + (size_t)(gn0 + rowbase + srow) * K_N + k0 + sch * 8;
      __builtin_amdgcn_global_load_lds((const __attribute__((address_space(1))) void*)g,
        (__attribute__((address_space(3))) void*)&Bs[buf][rowbase * 64], 16, 0, 0);
    }
  };

  bf16x8 a[4][2], b[2][2];

#define LOAD_A(BUF, MH) \
  _Pragma("unroll") for (int mi = 0; mi < 4; ++mi) \
  _Pragma("unroll") for (int kk = 0; kk < 2; ++kk) \
    a[mi][kk] = *(const bf16x8*)&As[BUF][(wr * 128 + (MH) * 64 + mi * 16 + rlo) * 64 + swz[kk]];
#define LOAD_B(BUF, NH) \
  _Pragma("unroll") for (int ni = 0; ni < 2; ++ni) \
  _Pragma("unroll") for (int kk = 0; kk < 2; ++kk) \
    b[ni][kk] = *(const bf16x8*)&Bs[BUF][(wc * 64 + (NH) * 32 + ni * 16 + rlo) * 64 + swz[kk]];
#define MFMA_Q(MI0, NI0) \
  __builtin_amdgcn_s_setprio(1); \
  _Pragma("unroll") for (int mi = 0; mi < 4; ++mi) \
  _Pragma("unroll") for (int ni = 0; ni < 2; ++ni) \
  _Pragma("unroll") for (int kk = 0; kk < 2; ++kk) \
    acc[(MI0) + mi][(NI0) + ni] = __builtin_amdgcn_mfma_f32_16x16x32_bf16( \
        a[mi][kk], b[ni][kk], acc[(MI0) + mi][(NI0) + ni], 0, 0, 0); \
  __builtin_amdgcn_s_setprio(0);
#define SYNC_MFMA \
  __builtin_amdgcn_s_barrier(); \
  asm volatile("s_waitcnt lgkmcnt(0)" ::: "memory"); \
  __builtin_amdgcn_sched_barrier(0);
#define ENDPH __builtin_amdgcn_s_barrier();

  // Prologue: tile0 fully into buf0; tile1's hA0,hB1 into buf1 (staged last).
  stageA(0, 0, 0); stageA(0, 1, 0); stageB(0, 0, 0); stageB(0, 1, 0);
  stageA(1, 0, 64); stageB(1, 1, 64);
  asm volatile("s_waitcnt vmcnt(4)" ::: "memory");   // buf0 landed
  __builtin_amdgcn_s_barrier();

  // Main: 5 iters cover tiles 0..9; all stages unconditional (kD <= 11*64).
  for (int i = 0; i < 5; ++i) {
    const int kB = (2 * i + 1) * 64;
    const int kC = (2 * i + 2) * 64;
    const int kD = (2 * i + 3) * 64;
    // P1: Q1 of tile 2i (buf0)
    LOAD_A(0, 0); LOAD_B(0, 0);
    stageB(1, 0, kB);
    SYNC_MFMA; MFMA_Q(0, 0); ENDPH;
    // P2
    LOAD_B(0, 1);
    stageA(1, 1, kB);
    SYNC_MFMA; MFMA_Q(0, 2); ENDPH;
    // P3
    LOAD_A(0, 1);
    stageA(0, 0, kC);
    SYNC_MFMA; MFMA_Q(4, 2); ENDPH;
    // P4
    LOAD_B(0, 0);
    stageB(0, 1, kC);
    asm volatile("s_waitcnt vmcnt(4)" ::: "memory");  // tile 2i+1 fully landed
    SYNC_MFMA; MFMA_Q(4, 0); ENDPH;
    // P5: Q1 of tile 2i+1 (buf1)
    LOAD_A(1, 0); LOAD_B(1, 0);
    stageB(0, 0, kC);
    SYNC_MFMA; MFMA_Q(0, 0); ENDPH;
    // P6
    LOAD_B(1, 1);
    stageA(0, 1, kC);
    SYNC_MFMA; MFMA_Q(0, 2); ENDPH;
    // P7
    LOAD_A(1, 1);
    stageA(1, 0, kD);
    SYNC_MFMA; MFMA_Q(4, 2); ENDPH;
    // P8
    LOAD_B(1, 0);
    stageB(1, 1, kD);
    asm volatile("s_waitcnt vmcnt(4)" ::: "memory");  // tile 2i+2 fully landed
    SYNC_MFMA; MFMA_Q(4, 0); ENDPH;
  }

  // Tail: tiles 10 (buf0), 11 (buf1). Remaining stages: B11.h0 (T1), A11.h1 (T2).
  {
    const int k11 = 11 * 64;
    // T1
    LOAD_A(0, 0); LOAD_B(0, 0);
    stageB(1, 0, k11);
    SYNC_MFMA; MFMA_Q(0, 0); ENDPH;
    // T2
    LOAD_B(0, 1);
    stageA(1, 1, k11);
    SYNC_MFMA; MFMA_Q(0, 2); ENDPH;
    // T3
    LOAD_A(0, 1);
    SYNC_MFMA; MFMA_Q(4, 2); ENDPH;
    // T4: FULL drain — all tile-11 halves (iter4 P7/P8 + T1/T2) must land.
    LOAD_B(0, 0);
    asm volatile("s_waitcnt vmcnt(0)" ::: "memory");
    SYNC_MFMA; MFMA_Q(4, 0); ENDPH;
    // T5
    LOAD_A(1, 0); LOAD_B(1, 0);
    SYNC_MFMA; MFMA_Q(0, 0); ENDPH;
    // T6
    LOAD_B(1, 1);
    SYNC_MFMA; MFMA_Q(0, 2); ENDPH;
    // T7
    LOAD_A(1, 1);
    SYNC_MFMA; MFMA_Q(4, 2); ENDPH;
    // T8
    LOAD_B(1, 0);
    SYNC_MFMA; MFMA_Q(4, 0); ENDPH;
  }

  // Epilogue: C/D layout col=lane&15, row=(lane>>4)*4+reg
  const int row0 = gm0 + wr * 128 + (lane >> 4) * 4;
  const int col0 = gn0 + wc * 64 + (lane & 15);
  #pragma unroll
  for (int mi = 0; mi < 8; ++mi)
    #pragma unroll
    for (int ni = 0; ni < 4; ++ni)
      #pragma unroll
      for (int r = 0; r < 4; ++r)
        out[(size_t)(row0 + mi * 16 + r) * E_N + (col0 + ni * 16)] = acc[mi][ni][r];
#undef LOAD_A
#undef LOAD_B
#undef MFMA_Q
#undef SYNC_MFMA
#undef ENDPH
}

extern "C" void kernel_launch(void* const* d_in, const int* in_sizes, int n_in,
                              void* d_out, int out_size, void* d_ws, size_t ws_size,
                              hipStream_t stream) {
  const float* img = (const float*)d_in[0];
  const int*   seg = (const int*)d_in[1];
  const float* cw  = (const float*)d_in[2];
  float* out = (float*)d_out;
  char* ws = (char*)d_ws;

  unsigned long long* partials = (unsigned long long*)ws;    // 8,388,608 B
  unsigned short* Bmat = (unsigned short*)(ws + 8388608);    // 1,179,648 B
  unsigned short* Amat = (unsigned short*)(ws + 9568256);    // 100,663,296 B

  k_accum_convw<<<1600, 256, 0, stream>>>(seg, partials, cw, Bmat);
  k_patch3<<<4096, 256, 0, stream>>>(img, partials, Amat);
  k_gemm8<<<768, 512, 0, stream>>>(Amat, Bmat, out);
}